// Round 6
// baseline (349.474 us; speedup 1.0000x reference)
//
#include <hip/hip_runtime.h>

// out[b,c,t,k,l] = x_pad[b,c,t+k] * W[l,k]
//   x: (B=2, C=1, T=2000) fp32 ; W: (L=101, K=200) fp32 -> out (2,1,2000,200,101) fp32
#define B_    2
#define T_    2000
#define K_    200
#define L_    101
#define ROW_  (K_ * L_)      // 20200 elements per (b,t) row
#define ROW4_ (ROW_ / 4)     // 5050 float4 per row
#define XP_   (T_ + K_)      // 2200 padded x per batch
#define RPB_  2              // rows per block
#define PAIRS_PER_B_ (T_ / RPB_)   // 1000

typedef float fx4 __attribute__((ext_vector_type(4)));  // true vector type:
// __builtin_nontemporal_store requires int/float/pointer or VECTOR of such —
// HIP's float4 (HIP_vector_type struct) is rejected (R4 compile error).

// ---- setup: transpose W -> Wt[k*L + l], pad x -> xp[b][0..XP_) ----
__global__ __launch_bounds__(256) void prep_kernel(const float* __restrict__ x,
                                                   const float* __restrict__ W,
                                                   float* __restrict__ Wt,
                                                   float* __restrict__ xp) {
    int tid = blockIdx.x * 256 + threadIdx.x;
    if (tid < ROW_) {
        int l = tid / K_;             // W is (L, K) row-major
        int k = tid - l * K_;
        Wt[k * L_ + l] = W[tid];      // Wt is (K, L): matches output inner layout
    }
    if (tid < B_ * XP_) {
        int b  = tid / XP_;
        int tt = tid - b * XP_;
        xp[tid] = (tt < T_) ? x[b * T_ + tt] : 0.0f;
    }
}

// ---- main: 2 rows per block; x window in LDS; nontemporal fx4 stores ----
__global__ __launch_bounds__(256) void expand_kernel(const float* __restrict__ xp,
                                                     const float* __restrict__ Wt,
                                                     float* __restrict__ out) {
    const int pair = blockIdx.x;                      // 0 .. B_*PAIRS_PER_B_-1
    const unsigned b = (unsigned)pair / (unsigned)PAIRS_PER_B_;
    const int t0 = (pair - (int)b * PAIRS_PER_B_) * RPB_;   // 0,2,..,1998

    // Stage x window: xwin[i] = x_pad[b, t0+i], i in [0, K_+RPB_-1) = [0,201)
    __shared__ float xwin[K_ + RPB_ + 8];
    const float* __restrict__ xsrc = xp + b * XP_ + t0;     // t0+200 <= 2198 < 2200, safe
    for (int i = threadIdx.x; i < K_ + RPB_ - 1; i += 256) xwin[i] = xsrc[i];
    __syncthreads();

    const size_t row0 = (size_t)(b * T_ + t0) * ROW_;
    fx4* __restrict__ o0 = (fx4*)(out + row0);         // 80800 B row stride, 16B-aligned
    fx4* __restrict__ o1 = (fx4*)(out + row0 + ROW_);
    const fx4* __restrict__ w4 = (const fx4*)Wt;

    #pragma unroll 4
    for (int j4 = threadIdx.x; j4 < ROW4_; j4 += 256) {
        fx4 w = w4[j4];                     // L2-resident, coalesced 16B load
        int j = j4 * 4;                     // j = k*101 + l
        unsigned k0 = (unsigned)j / (unsigned)L_;   // one magic-mul division
        unsigned r0 = (unsigned)j - k0 * L_;        // 0..100
        unsigned k1 = k0 + (r0 >= 100);             // k for j+1 (steps of +1 only: 101 > 4)
        unsigned k2 = k0 + (r0 >= 99);
        unsigned k3 = k0 + (r0 >= 98);
        fx4 r0v, r1v;
        r0v.x = w.x * xwin[k0];  r1v.x = w.x * xwin[k0 + 1];   // LDS broadcast reads
        r0v.y = w.y * xwin[k1];  r1v.y = w.y * xwin[k1 + 1];
        r0v.z = w.z * xwin[k2];  r1v.z = w.z * xwin[k2 + 1];
        r0v.w = w.w * xwin[k3];  r1v.w = w.w * xwin[k3 + 1];
        __builtin_nontemporal_store(r0v, o0 + j4);  // write-once stream: bypass L2 pollution
        __builtin_nontemporal_store(r1v, o1 + j4);
    }
}

// ---- fallback (no workspace): direct reads, bounds-checked ----
__global__ __launch_bounds__(256) void expand_fallback(const float* __restrict__ x,
                                                       const float* __restrict__ W,
                                                       float* __restrict__ out) {
    const int row = blockIdx.x;
    const unsigned b = (unsigned)row / (unsigned)T_;
    const int t = row - (int)b * T_;
    const float* __restrict__ xb = x + b * T_;
    float* __restrict__ orow = out + (size_t)row * ROW_;
    for (int j = threadIdx.x; j < ROW_; j += 256) {
        unsigned k = (unsigned)j / (unsigned)L_;
        unsigned l = (unsigned)j - k * (unsigned)L_;
        float xv = (t + (int)k < T_) ? xb[t + k] : 0.0f;
        orow[j] = xv * W[l * K_ + k];
    }
}

extern "C" void kernel_launch(void* const* d_in, const int* in_sizes, int n_in,
                              void* d_out, int out_size, void* d_ws, size_t ws_size,
                              hipStream_t stream) {
    const float* x = (const float*)d_in[0];   // (B, C=1, T) fp32
    const float* W = (const float*)d_in[1];   // (L, K) fp32
    float* out = (float*)d_out;               // (B, 1, T, K, L) fp32

    const size_t ws_needed = (size_t)(ROW_ + B_ * XP_) * sizeof(float); // 98,400 B
    if (ws_size >= ws_needed && d_ws != nullptr) {
        float* Wt = (float*)d_ws;             // 20200 floats
        float* xp = Wt + ROW_;                // offset 80800 B, 16B-aligned
        prep_kernel<<<(ROW_ + 255) / 256, 256, 0, stream>>>(x, W, Wt, xp);
        expand_kernel<<<B_ * PAIRS_PER_B_, 256, 0, stream>>>(xp, Wt, out);
    } else {
        expand_fallback<<<B_ * T_, 256, 0, stream>>>(x, W, out);
    }
}